// Round 5
// baseline (331.953 us; speedup 1.0000x reference)
//
#include <hip/hip_runtime.h>
#include <hip/hip_bf16.h>
#include <math.h>

#define N_IN 28
#define N_MID 256
#define N_OUT 28
#define SEQ 28
#define BATCH 4096
#define ROWS 16
#define THREADS 512
#define NBLK (BATCH / ROWS)   // 256

typedef __attribute__((ext_vector_type(8))) short bf16x8;
typedef __attribute__((ext_vector_type(4))) float f32x4;

#define MFMA(a, b, c) __builtin_amdgcn_mfma_f32_16x16x32_bf16((a), (b), (c), 0, 0, 0)

__device__ __forceinline__ short f2bf(float v) {
    __hip_bfloat16 b = __float2bfloat16(v);
    return *reinterpret_cast<short*>(&b);
}
__device__ __forceinline__ float bf2f(short s) {
    unsigned int u = ((unsigned int)(unsigned short)s) << 16;
    return __uint_as_float(u);
}
__device__ __forceinline__ float fsigmoid(float v) {
    return 1.0f / (1.0f + __expf(-v));
}
__device__ __forceinline__ float ftanh(float v) {
    float e = __expf(2.0f * v);
    return 1.0f - 2.0f / (e + 1.0f);
}

// One GRU timestep. RB = read buffer (t&1), writes RB^1. HID=false skips the
// hidden projection (t=0, h=0). All weight B-fragments live in registers.
template<bool HID, int RB>
__device__ __forceinline__ void gru_step(
    int t, const float* __restrict__ x, int rowbase,
    int l15, int lg,
    short (&hl)[2][2][32][17][8],
    const bf16x8 (&wreg)[3][2][8],
    const bf16x8 (&wireg)[3][2],
    const float (&bR)[2], const float (&bZ)[2],
    const float (&bIN)[2], const float (&bHN)[2],
    float (&hold)[2][4], const int (&colA)[2])
{
    constexpr int WB = RB ^ 1;

    // issue x global load early (consumed only after hidden MFMAs)
    const float* xp = x + (size_t)(rowbase + l15) * (SEQ * N_IN) + t * N_IN + lg * 8;
    float4 xa = *(const float4*)xp;
    float4 xb;
    xb.x = 0.f; xb.y = 0.f; xb.z = 0.f; xb.w = 0.f;
    if (lg < 3) xb = *(const float4*)(xp + 4);

    // batched h A-fragment prefetch (16 x ds_read_b128, pipelined)
    bf16x8 ah[8], al[8];
    if constexpr (HID) {
        #pragma unroll
        for (int ks = 0; ks < 8; ++ks) {
            ah[ks] = *(const bf16x8*)&hl[RB][0][ks * 4 + lg][l15][0];
            al[ks] = *(const bf16x8*)&hl[RB][1][ks * 4 + lg][l15][0];
        }
    }

    f32x4 aR[2], aZ[2], aIN[2], aHN[2];
    #pragma unroll
    for (int a = 0; a < 2; ++a) {
        aR[a]  = (f32x4){bR[a],  bR[a],  bR[a],  bR[a]};
        aZ[a]  = (f32x4){bZ[a],  bZ[a],  bZ[a],  bZ[a]};
        aIN[a] = (f32x4){bIN[a], bIN[a], bIN[a], bIN[a]};
        aHN[a] = (f32x4){bHN[a], bHN[a], bHN[a], bHN[a]};
    }

    if constexpr (HID) {
        __builtin_amdgcn_s_setprio(1);
        #pragma unroll
        for (int ks = 0; ks < 8; ++ks) {
            #pragma unroll
            for (int a = 0; a < 2; ++a) {
                aR[a]  = MFMA(ah[ks], wreg[0][a][ks], aR[a]);
                aR[a]  = MFMA(al[ks], wreg[0][a][ks], aR[a]);
                aZ[a]  = MFMA(ah[ks], wreg[1][a][ks], aZ[a]);
                aZ[a]  = MFMA(al[ks], wreg[1][a][ks], aZ[a]);
                aHN[a] = MFMA(ah[ks], wreg[2][a][ks], aHN[a]);
                aHN[a] = MFMA(al[ks], wreg[2][a][ks], aHN[a]);
            }
        }
        __builtin_amdgcn_s_setprio(0);
    }

    // x conversion + input projection (x load latency hidden by MFMAs above)
    float xv[8] = {xa.x, xa.y, xa.z, xa.w, xb.x, xb.y, xb.z, xb.w};
    bf16x8 xh, xlo;
    #pragma unroll
    for (int e = 0; e < 8; ++e) {
        short h = f2bf(xv[e]);
        xh[e]  = h;
        xlo[e] = f2bf(xv[e] - bf2f(h));
    }
    #pragma unroll
    for (int a = 0; a < 2; ++a) {
        aR[a]  = MFMA(xh, wireg[0][a], aR[a]);   aR[a]  = MFMA(xlo, wireg[0][a], aR[a]);
        aZ[a]  = MFMA(xh, wireg[1][a], aZ[a]);   aZ[a]  = MFMA(xlo, wireg[1][a], aZ[a]);
        aIN[a] = MFMA(xh, wireg[2][a], aIN[a]);  aIN[a] = MFMA(xlo, wireg[2][a], aIN[a]);
    }

    // lane-local GRU update; write h(t+1) A-fragments
    #pragma unroll
    for (int a = 0; a < 2; ++a) {
        const int c = colA[a];
        #pragma unroll
        for (int j = 0; j < 4; ++j) {
            float r = fsigmoid(aR[a][j]);
            float z = fsigmoid(aZ[a][j]);
            float n = ftanh(aIN[a][j] + r * aHN[a][j]);
            float hnew = fmaf(z, hold[a][j] - n, n);   // n + z*(h-n)
            hold[a][j] = hnew;
            short hi = f2bf(hnew);
            short lo = f2bf(hnew - bf2f(hi));
            hl[WB][0][c >> 3][4 * lg + j][c & 7] = hi;
            hl[WB][1][c >> 3][4 * lg + j][c & 7] = lo;
        }
    }
    __syncthreads();
}

__global__ __launch_bounds__(THREADS, 1) void gru_fused(
    const float* __restrict__ x,     // [B][T][28]
    const float* __restrict__ w_ih,  // [768][28]
    const float* __restrict__ w_hh,  // [768][256]
    const float* __restrict__ b_ih,
    const float* __restrict__ b_hh,
    const float* __restrict__ fc_w,  // [28][256]
    const float* __restrict__ fc_b,
    float* __restrict__ out)         // [B][28]
{
    __shared__ short hl[2][2][32][17][8];   // 68 KB h double-buffer (A-frag layout)
    __shared__ float hfc[ROWS][257];        // 16.4 KB FC scratch  (84 KB total -> 1 blk/CU)

    const int tid  = threadIdx.x;
    const int lane = tid & 63;
    const int l15  = lane & 15;
    const int lg   = lane >> 4;
    const int wv   = tid >> 6;              // wave owns cols [32wv, 32wv+32)
    const int rowbase = blockIdx.x * ROWS;

    // ---- one-time: ALL w_hh / w_ih B-fragments into registers, f32 -> bf16
    bf16x8 wreg[3][2][8];
    bf16x8 wireg[3][2];
    int   colA[2];
    float bR[2], bZ[2], bIN[2], bHN[2];
    #pragma unroll
    for (int a = 0; a < 2; ++a) {
        const int c = wv * 32 + a * 16 + l15;
        colA[a] = c;
        bR[a]  = b_ih[c]       + b_hh[c];
        bZ[a]  = b_ih[256 + c] + b_hh[256 + c];
        bIN[a] = b_ih[512 + c];
        bHN[a] = b_hh[512 + c];
        #pragma unroll
        for (int g = 0; g < 3; ++g) {
            const float* wb = w_hh + (size_t)(g * 256 + c) * 256 + lg * 8;
            #pragma unroll
            for (int ks = 0; ks < 8; ++ks) {
                float4 v0 = *(const float4*)(wb + ks * 32);
                float4 v1 = *(const float4*)(wb + ks * 32 + 4);
                bf16x8 d;
                d[0] = f2bf(v0.x); d[1] = f2bf(v0.y); d[2] = f2bf(v0.z); d[3] = f2bf(v0.w);
                d[4] = f2bf(v1.x); d[5] = f2bf(v1.y); d[6] = f2bf(v1.z); d[7] = f2bf(v1.w);
                wreg[g][a][ks] = d;
            }
            bf16x8 di;
            #pragma unroll
            for (int e = 0; e < 8; ++e) {
                int k = lg * 8 + e;
                di[e] = (k < N_IN) ? f2bf(w_ih[(size_t)(g * 256 + c) * N_IN + k])
                                   : (short)0;
            }
            wireg[g][a] = di;
        }
    }

    float hold[2][4] = {};

    __syncthreads();   // not strictly needed (no LDS written yet) but cheap

    // t=0: h=0, skip hidden projection, writes buf1
    gru_step<false, 0>(0, x, rowbase, l15, lg, hl, wreg, wireg,
                       bR, bZ, bIN, bHN, hold, colA);
    // t=1..26 in compile-time-buffered pairs
    for (int tt = 1; tt < SEQ - 1; tt += 2) {
        gru_step<true, 1>(tt,     x, rowbase, l15, lg, hl, wreg, wireg,
                          bR, bZ, bIN, bHN, hold, colA);
        gru_step<true, 0>(tt + 1, x, rowbase, l15, lg, hl, wreg, wireg,
                          bR, bZ, bIN, bHN, hold, colA);
    }
    // t=27 reads buf1, writes buf0 -> h(SEQ) in buf0
    gru_step<true, 1>(SEQ - 1, x, rowbase, l15, lg, hl, wreg, wireg,
                      bR, bZ, bIN, bHN, hold, colA);

    // ---- FC epilogue
    {
        int r = tid >> 5, kg = tid & 31;
        #pragma unroll
        for (int e = 0; e < 8; ++e) {
            int k = kg * 8 + e;
            hfc[r][k] = bf2f(hl[0][0][k >> 3][r][k & 7]) +
                        bf2f(hl[0][1][k >> 3][r][k & 7]);
        }
    }
    __syncthreads();
    if (tid < ROWS * N_OUT) {
        int r = tid / N_OUT, o = tid - r * N_OUT;
        float acc = fc_b[o];
        #pragma unroll 8
        for (int k = 0; k < N_MID; ++k)
            acc = fmaf(hfc[r][k], fc_w[o * 256 + k], acc);
        out[(size_t)(rowbase + r) * N_OUT + o] = acc;
    }
}

extern "C" void kernel_launch(void* const* d_in, const int* in_sizes, int n_in,
                              void* d_out, int out_size, void* d_ws, size_t ws_size,
                              hipStream_t stream) {
    const float* x    = (const float*)d_in[0];
    const float* w_ih = (const float*)d_in[1];
    const float* w_hh = (const float*)d_in[2];
    const float* b_ih = (const float*)d_in[3];
    const float* b_hh = (const float*)d_in[4];
    const float* fc_w = (const float*)d_in[5];
    const float* fc_b = (const float*)d_in[6];
    float* out = (float*)d_out;

    hipLaunchKernelGGL(gru_fused, dim3(NBLK), dim3(THREADS), 0, stream,
                       x, w_ih, w_hh, b_ih, b_hh, fc_w, fc_b, out);
}

// Round 6
// 131.202 us; speedup vs baseline: 2.5301x; 2.5301x over previous
//
#include <hip/hip_runtime.h>
#include <hip/hip_bf16.h>
#include <math.h>

#define N_IN 28
#define N_MID 256
#define N_OUT 28
#define SEQ 28
#define BATCH 4096
#define G3 768
#define ROWS 16
#define THREADS 512
#define NBLK (BATCH / ROWS)   // 256

typedef __attribute__((ext_vector_type(8))) short bf16x8;
typedef __attribute__((ext_vector_type(4))) float f32x4;

#define MFMA(a, b, c) __builtin_amdgcn_mfma_f32_16x16x32_bf16((a), (b), (c), 0, 0, 0)

__device__ __forceinline__ short f2bf(float v) {
    __hip_bfloat16 b = __float2bfloat16(v);
    return *reinterpret_cast<short*>(&b);
}
__device__ __forceinline__ float bf2f(short s) {
    unsigned int u = ((unsigned int)(unsigned short)s) << 16;
    return __uint_as_float(u);
}
__device__ __forceinline__ float fsigmoid(float v) {
    return 1.0f / (1.0f + __expf(-v));
}
__device__ __forceinline__ float ftanh(float v) {
    float e = __expf(2.0f * v);
    return 1.0f - 2.0f / (e + 1.0f);
}

// prep: w_hh [768][256] f32 -> wB bf16; w_ih [768][28] -> wI bf16 [768][32] padded
__global__ void prep_w(const float* __restrict__ w_hh, const float* __restrict__ w_ih,
                       short* __restrict__ wB, short* __restrict__ wI) {
    int idx = blockIdx.x * 256 + threadIdx.x;
    if (idx < G3 * N_MID) wB[idx] = f2bf(w_hh[idx]);
    if (idx < G3 * 32) {
        int g = idx >> 5, k = idx & 31;
        float v = (k < N_IN) ? w_ih[g * N_IN + k] : 0.0f;
        wI[idx] = f2bf(v);
    }
}

// One timestep. RB = read buffer, writes RB^1. HID=false: t=0, h=0.
// Precision: R,Z gates use h-hi only (sigmoid-attenuated); N gate dual hi/lo.
template<bool HID, int RB>
__device__ __forceinline__ void gru_step(
    int t, const float* __restrict__ x, int rowbase,
    int l15, int lg, int wv, int lane,
    short (&hl)[2][2][32][17][8],
    const short (&wlds)[2][3][16][64][8],
    const bf16x8 (&wreg)[3][2][6],
    const bf16x8 (&wireg)[3][2],
    const float (&bR)[2], const float (&bZ)[2],
    const float (&bIN)[2], const float (&bHN)[2],
    float (&hold)[2][4], const int (&colA)[2])
{
    constexpr int WB = RB ^ 1;

    // issue x global load early (consumed only after hidden MFMAs)
    const float* xp = x + (size_t)(rowbase + l15) * (SEQ * N_IN) + t * N_IN + lg * 8;
    float4 xa = *(const float4*)xp;
    float4 xb;
    xb.x = 0.f; xb.y = 0.f; xb.z = 0.f; xb.w = 0.f;
    if (lg < 3) xb = *(const float4*)(xp + 4);

    f32x4 aR[2], aZ[2], aIN[2], aHN[2];
    #pragma unroll
    for (int a = 0; a < 2; ++a) {
        aR[a]  = (f32x4){bR[a],  bR[a],  bR[a],  bR[a]};
        aZ[a]  = (f32x4){bZ[a],  bZ[a],  bZ[a],  bZ[a]};
        aIN[a] = (f32x4){bIN[a], bIN[a], bIN[a], bIN[a]};
        aHN[a] = (f32x4){bHN[a], bHN[a], bHN[a], bHN[a]};
    }

    if constexpr (HID) {
        // depth-2 pipelined hi-fragments; lo JIT (feeds only trailing N MFMAs)
        bf16x8 ah2[2];
        ah2[0] = *(const bf16x8*)&hl[RB][0][lg][l15][0];
        __builtin_amdgcn_s_setprio(1);
        #pragma unroll
        for (int ks = 0; ks < 8; ++ks) {
            const int cur = ks & 1, nxt = cur ^ 1;
            if (ks < 7)
                ah2[nxt] = *(const bf16x8*)&hl[RB][0][(ks + 1) * 4 + lg][l15][0];
            bf16x8 al = *(const bf16x8*)&hl[RB][1][ks * 4 + lg][l15][0];
            #pragma unroll
            for (int a = 0; a < 2; ++a) {
                bf16x8 b0, b1, b2;
                if (ks < 6) {
                    b0 = wreg[0][a][ks]; b1 = wreg[1][a][ks]; b2 = wreg[2][a][ks];
                } else {
                    const int cg = 2 * wv + a;
                    b0 = *(const bf16x8*)&wlds[ks - 6][0][cg][lane][0];
                    b1 = *(const bf16x8*)&wlds[ks - 6][1][cg][lane][0];
                    b2 = *(const bf16x8*)&wlds[ks - 6][2][cg][lane][0];
                }
                aR[a]  = MFMA(ah2[cur], b0, aR[a]);
                aZ[a]  = MFMA(ah2[cur], b1, aZ[a]);
                aHN[a] = MFMA(ah2[cur], b2, aHN[a]);
                aHN[a] = MFMA(al,       b2, aHN[a]);
            }
        }
        __builtin_amdgcn_s_setprio(0);
    }

    // x conversion + input projection (R,Z single-pass; N dual)
    float xv[8] = {xa.x, xa.y, xa.z, xa.w, xb.x, xb.y, xb.z, xb.w};
    bf16x8 xh, xlo;
    #pragma unroll
    for (int e = 0; e < 8; ++e) {
        short h = f2bf(xv[e]);
        xh[e]  = h;
        xlo[e] = f2bf(xv[e] - bf2f(h));
    }
    #pragma unroll
    for (int a = 0; a < 2; ++a) {
        aR[a]  = MFMA(xh,  wireg[0][a], aR[a]);
        aZ[a]  = MFMA(xh,  wireg[1][a], aZ[a]);
        aIN[a] = MFMA(xh,  wireg[2][a], aIN[a]);
        aIN[a] = MFMA(xlo, wireg[2][a], aIN[a]);
    }

    // lane-local GRU update; write h(t+1) A-fragments
    #pragma unroll
    for (int a = 0; a < 2; ++a) {
        const int c = colA[a];
        #pragma unroll
        for (int j = 0; j < 4; ++j) {
            float r = fsigmoid(aR[a][j]);
            float z = fsigmoid(aZ[a][j]);
            float n = ftanh(aIN[a][j] + r * aHN[a][j]);
            float hnew = fmaf(z, hold[a][j] - n, n);
            hold[a][j] = hnew;
            short hi = f2bf(hnew);
            short lo = f2bf(hnew - bf2f(hi));
            hl[WB][0][c >> 3][4 * lg + j][c & 7] = hi;
            hl[WB][1][c >> 3][4 * lg + j][c & 7] = lo;
        }
    }
    __syncthreads();
}

__global__ __launch_bounds__(THREADS, 2) void gru_onecu(
    const float* __restrict__ x,     // [B][T][28]
    const short* __restrict__ wB,    // [768][256] bf16
    const short* __restrict__ wI,    // [768][32] bf16
    const float* __restrict__ b_ih,
    const float* __restrict__ b_hh,
    const float* __restrict__ fc_w,  // [28][256]
    const float* __restrict__ fc_b,
    float* __restrict__ out)         // [B][28]
{
    // Weight K-slices 6,7 as frag-linear B-fragments (96 KB)
    __shared__ short wlds[2][3][16][64][8];
    // h double-buffer A-fragments: [buf][prec][kchunk][row(pad 17)][pos] (34 KB)
    __shared__ short hl[2][2][32][17][8];

    const int tid  = threadIdx.x;
    const int lane = tid & 63;
    const int l15  = lane & 15;
    const int lg   = lane >> 4;
    const int wv   = tid >> 6;              // wave owns cols [32wv, 32wv+32)
    const int rowbase = blockIdx.x * ROWS;

    // ---- one-time: stage K-slices 6,7 into LDS (frag-linear, conflict-free)
    for (int idx = tid; idx < 2 * 3 * 16 * 64; idx += THREADS) {
        int L    = idx & 63;
        int frag = idx >> 6;
        int ksl  = frag / 48;
        int rem  = frag - ksl * 48;
        int g    = rem >> 4;
        int cg   = rem & 15;
        int col  = cg * 16 + (L & 15);
        int k0   = (6 + ksl) * 32 + (L >> 4) * 8;
        *(bf16x8*)&wlds[ksl][g][cg][L][0] =
            *(const bf16x8*)(wB + ((size_t)(g * 256 + col)) * 256 + k0);
    }

    // ---- one-time: K-slices 0..5 + w_ih into registers, biases
    bf16x8 wreg[3][2][6];
    bf16x8 wireg[3][2];
    int   colA[2];
    float bR[2], bZ[2], bIN[2], bHN[2];
    #pragma unroll
    for (int a = 0; a < 2; ++a) {
        const int c = wv * 32 + a * 16 + l15;
        colA[a] = c;
        bR[a]  = b_ih[c]       + b_hh[c];
        bZ[a]  = b_ih[256 + c] + b_hh[256 + c];
        bIN[a] = b_ih[512 + c];
        bHN[a] = b_hh[512 + c];
        #pragma unroll
        for (int g = 0; g < 3; ++g) {
            wireg[g][a] = *(const bf16x8*)(wI + ((size_t)(g * 256 + c)) * 32 + lg * 8);
            #pragma unroll
            for (int ks = 0; ks < 6; ++ks)
                wreg[g][a][ks] =
                    *(const bf16x8*)(wB + ((size_t)(g * 256 + c)) * 256 + ks * 32 + lg * 8);
        }
    }

    float hold[2][4] = {};

    __syncthreads();

    // t=0 (h=0) writes buf1; pairs keep compile-time buffer indices
    gru_step<false, 0>(0, x, rowbase, l15, lg, wv, lane, hl, wlds, wreg, wireg,
                       bR, bZ, bIN, bHN, hold, colA);
    for (int tt = 1; tt < SEQ - 1; tt += 2) {
        gru_step<true, 1>(tt,     x, rowbase, l15, lg, wv, lane, hl, wlds, wreg, wireg,
                          bR, bZ, bIN, bHN, hold, colA);
        gru_step<true, 0>(tt + 1, x, rowbase, l15, lg, wv, lane, hl, wlds, wreg, wireg,
                          bR, bZ, bIN, bHN, hold, colA);
    }
    gru_step<true, 1>(SEQ - 1, x, rowbase, l15, lg, wv, lane, hl, wlds, wreg, wireg,
                      bR, bZ, bIN, bHN, hold, colA);

    // ---- FC epilogue: h(SEQ) in buf0
    float* hf = (float*)&wlds[0][0][0][0][0];   // overlay 16 KB on weight LDS
    {
        int r = tid >> 5, kg = tid & 31;
        #pragma unroll
        for (int e = 0; e < 8; ++e) {
            int k = kg * 8 + e;
            hf[r * 256 + k] = bf2f(hl[0][0][k >> 3][r][k & 7]) +
                              bf2f(hl[0][1][k >> 3][r][k & 7]);
        }
    }
    __syncthreads();
    if (tid < ROWS * N_OUT) {
        int r = tid / N_OUT, o = tid - r * N_OUT;
        float acc = fc_b[o];
        #pragma unroll
        for (int k4 = 0; k4 < 64; ++k4) {
            float4 hv = *(const float4*)&hf[r * 256 + k4 * 4];
            float4 wv4 = *(const float4*)&fc_w[o * 256 + k4 * 4];
            acc = fmaf(hv.x, wv4.x, acc);
            acc = fmaf(hv.y, wv4.y, acc);
            acc = fmaf(hv.z, wv4.z, acc);
            acc = fmaf(hv.w, wv4.w, acc);
        }
        out[(size_t)(rowbase + r) * N_OUT + o] = acc;
    }
}

extern "C" void kernel_launch(void* const* d_in, const int* in_sizes, int n_in,
                              void* d_out, int out_size, void* d_ws, size_t ws_size,
                              hipStream_t stream) {
    const float* x    = (const float*)d_in[0];
    const float* w_ih = (const float*)d_in[1];
    const float* w_hh = (const float*)d_in[2];
    const float* b_ih = (const float*)d_in[3];
    const float* b_hh = (const float*)d_in[4];
    const float* fc_w = (const float*)d_in[5];
    const float* fc_b = (const float*)d_in[6];
    float* out = (float*)d_out;

    short* wB = (short*)d_ws;                 // [768][256] bf16 = 384 KB
    short* wI = wB + G3 * N_MID;              // [768][32]  bf16 =  48 KB

    hipLaunchKernelGGL(prep_w, dim3(768), dim3(256), 0, stream, w_hh, w_ih, wB, wI);
    hipLaunchKernelGGL(gru_onecu, dim3(NBLK), dim3(THREADS), 0, stream,
                       x, wB, wI, b_ih, b_hh, fc_w, fc_b, out);
}

// Round 7
// 118.629 us; speedup vs baseline: 2.7982x; 1.1060x over previous
//
#include <hip/hip_runtime.h>
#include <hip/hip_bf16.h>
#include <math.h>

#define N_IN 28
#define N_MID 256
#define N_OUT 28
#define SEQ 28
#define BATCH 4096
#define G3 768
#define ROWS 16
#define THREADS 512
#define NBLK (BATCH / ROWS)   // 256

typedef __attribute__((ext_vector_type(8))) short bf16x8;
typedef __attribute__((ext_vector_type(4))) float f32x4;

#define MFMA(a, b, c) __builtin_amdgcn_mfma_f32_16x16x32_bf16((a), (b), (c), 0, 0, 0)

__device__ __forceinline__ short f2bf(float v) {          // RNE (stored h)
    __hip_bfloat16 b = __float2bfloat16(v);
    return *reinterpret_cast<short*>(&b);
}
__device__ __forceinline__ float bf2f(short s) {
    unsigned int u = ((unsigned int)(unsigned short)s) << 16;
    return __uint_as_float(u);
}
__device__ __forceinline__ float fsigmoid(float v) {
    return 1.0f / (1.0f + __expf(-v));
}
__device__ __forceinline__ float ftanh(float v) {
    float e = __expf(2.0f * v);
    return 1.0f - 2.0f / (e + 1.0f);
}

// prep: w_hh [768][256] f32 -> wB bf16; w_ih [768][28] -> wI bf16 [768][32] padded
__global__ void prep_w(const float* __restrict__ w_hh, const float* __restrict__ w_ih,
                       short* __restrict__ wB, short* __restrict__ wI) {
    int idx = blockIdx.x * 256 + threadIdx.x;
    if (idx < G3 * N_MID) wB[idx] = f2bf(w_hh[idx]);
    if (idx < G3 * 32) {
        int g = idx >> 5, k = idx & 31;
        float v = (k < N_IN) ? w_ih[g * N_IN + k] : 0.0f;
        wI[idx] = f2bf(v);
    }
}

// One timestep. RB = read buffer, writes RB^1. HID=false: t=0 (h=0).
// h is single RNE bf16; x is trunc hi/lo (combined ~2^-17, feeds N gate dual).
template<bool HID, int RB>
__device__ __forceinline__ void gru_step(
    int t, const float* __restrict__ x, int rowbase,
    int l15, int lg, int wv, int lane,
    short (&hl)[2][32][17][8],
    const short (&wlds)[2][3][16][64][8],
    const bf16x8 (&wreg)[3][2][6],
    const bf16x8 (&wireg)[3][2],
    const float (&bR)[2], const float (&bZ)[2],
    const float (&bIN)[2], const float (&bHN)[2],
    float (&hold)[2][4], const int (&colA)[2])
{
    constexpr int WB = RB ^ 1;

    // issue x global load early (consumed after hidden MFMAs)
    const float* xp = x + (size_t)(rowbase + l15) * (SEQ * N_IN) + t * N_IN + lg * 8;
    float4 xa = *(const float4*)xp;
    float4 xb;
    xb.x = 0.f; xb.y = 0.f; xb.z = 0.f; xb.w = 0.f;
    if (lg < 3) xb = *(const float4*)(xp + 4);

    f32x4 aR[2], aZ[2], aIN[2], aHN[2];
    #pragma unroll
    for (int a = 0; a < 2; ++a) {
        aR[a]  = (f32x4){bR[a],  bR[a],  bR[a],  bR[a]};
        aZ[a]  = (f32x4){bZ[a],  bZ[a],  bZ[a],  bZ[a]};
        aIN[a] = (f32x4){bIN[a], bIN[a], bIN[a], bIN[a]};
        aHN[a] = (f32x4){bHN[a], bHN[a], bHN[a], bHN[a]};
    }

    if constexpr (HID) {
        // K-slice order {6,7,0..5}: LDS-B slices first so their 12 reads
        // pipeline together with the ah reads; reg-B slices consume during drain.
        constexpr int ord[8] = {6, 7, 0, 1, 2, 3, 4, 5};
        bf16x8 ah2[2];
        ah2[0] = *(const bf16x8*)&hl[RB][ord[0] * 4 + lg][l15][0];
        __builtin_amdgcn_s_setprio(1);
        #pragma unroll
        for (int i = 0; i < 8; ++i) {
            const int ks = ord[i];
            const int cur = i & 1, nxt = cur ^ 1;
            if (i < 7)
                ah2[nxt] = *(const bf16x8*)&hl[RB][ord[i + 1] * 4 + lg][l15][0];
            #pragma unroll
            for (int a = 0; a < 2; ++a) {
                bf16x8 b0, b1, b2;
                if (ks < 6) {
                    b0 = wreg[0][a][ks]; b1 = wreg[1][a][ks]; b2 = wreg[2][a][ks];
                } else {
                    const int cg = 2 * wv + a;
                    b0 = *(const bf16x8*)&wlds[ks - 6][0][cg][lane][0];
                    b1 = *(const bf16x8*)&wlds[ks - 6][1][cg][lane][0];
                    b2 = *(const bf16x8*)&wlds[ks - 6][2][cg][lane][0];
                }
                aR[a]  = MFMA(ah2[cur], b0, aR[a]);
                aZ[a]  = MFMA(ah2[cur], b1, aZ[a]);
                aHN[a] = MFMA(ah2[cur], b2, aHN[a]);
            }
        }
        __builtin_amdgcn_s_setprio(0);
    }

    // x trunc hi/lo split (cheap bit ops) + input projection
    float xv[8] = {xa.x, xa.y, xa.z, xa.w, xb.x, xb.y, xb.z, xb.w};
    bf16x8 xh, xlo;
    #pragma unroll
    for (int e = 0; e < 8; ++e) {
        unsigned int u = __float_as_uint(xv[e]);
        xh[e] = (short)(u >> 16);
        float rem = xv[e] - __uint_as_float(u & 0xffff0000u);
        xlo[e] = (short)(__float_as_uint(rem) >> 16);
    }
    #pragma unroll
    for (int a = 0; a < 2; ++a) {
        aR[a]  = MFMA(xh,  wireg[0][a], aR[a]);
        aZ[a]  = MFMA(xh,  wireg[1][a], aZ[a]);
        aIN[a] = MFMA(xh,  wireg[2][a], aIN[a]);
        aIN[a] = MFMA(xlo, wireg[2][a], aIN[a]);
    }

    // lane-local GRU update; write h(t+1) A-fragments (RNE bf16)
    #pragma unroll
    for (int a = 0; a < 2; ++a) {
        const int c = colA[a];
        #pragma unroll
        for (int j = 0; j < 4; ++j) {
            float r = fsigmoid(aR[a][j]);
            float z = fsigmoid(aZ[a][j]);
            float n = ftanh(aIN[a][j] + r * aHN[a][j]);
            float hnew = fmaf(z, hold[a][j] - n, n);
            hold[a][j] = hnew;
            hl[WB][c >> 3][4 * lg + j][c & 7] = f2bf(hnew);
        }
    }
    __syncthreads();
}

__global__ __launch_bounds__(THREADS, 2) void gru_onecu(
    const float* __restrict__ x,     // [B][T][28]
    const short* __restrict__ wB,    // [768][256] bf16
    const short* __restrict__ wI,    // [768][32] bf16
    const float* __restrict__ b_ih,
    const float* __restrict__ b_hh,
    const float* __restrict__ fc_w,  // [28][256]
    const float* __restrict__ fc_b,
    float* __restrict__ out)         // [B][28]
{
    // Weight K-slices 6,7 as frag-linear B-fragments (96 KB)
    __shared__ short wlds[2][3][16][64][8];
    // h double-buffer A-fragments, single bf16: [buf][kchunk][row(pad17)][pos] (17 KB)
    __shared__ short hl[2][32][17][8];

    const int tid  = threadIdx.x;
    const int lane = tid & 63;
    const int l15  = lane & 15;
    const int lg   = lane >> 4;
    const int wv   = tid >> 6;              // wave owns cols [32wv, 32wv+32)
    const int rowbase = blockIdx.x * ROWS;

    // ---- one-time: stage K-slices 6,7 into LDS (frag-linear, conflict-free)
    for (int idx = tid; idx < 2 * 3 * 16 * 64; idx += THREADS) {
        int L    = idx & 63;
        int frag = idx >> 6;
        int ksl  = frag / 48;
        int rem  = frag - ksl * 48;
        int g    = rem >> 4;
        int cg   = rem & 15;
        int col  = cg * 16 + (L & 15);
        int k0   = (6 + ksl) * 32 + (L >> 4) * 8;
        *(bf16x8*)&wlds[ksl][g][cg][L][0] =
            *(const bf16x8*)(wB + ((size_t)(g * 256 + col)) * 256 + k0);
    }

    // ---- one-time: K-slices 0..5 + w_ih into registers, biases
    bf16x8 wreg[3][2][6];
    bf16x8 wireg[3][2];
    int   colA[2];
    float bR[2], bZ[2], bIN[2], bHN[2];
    #pragma unroll
    for (int a = 0; a < 2; ++a) {
        const int c = wv * 32 + a * 16 + l15;
        colA[a] = c;
        bR[a]  = b_ih[c]       + b_hh[c];
        bZ[a]  = b_ih[256 + c] + b_hh[256 + c];
        bIN[a] = b_ih[512 + c];
        bHN[a] = b_hh[512 + c];
        #pragma unroll
        for (int g = 0; g < 3; ++g) {
            wireg[g][a] = *(const bf16x8*)(wI + ((size_t)(g * 256 + c)) * 32 + lg * 8);
            #pragma unroll
            for (int ks = 0; ks < 6; ++ks)
                wreg[g][a][ks] =
                    *(const bf16x8*)(wB + ((size_t)(g * 256 + c)) * 256 + ks * 32 + lg * 8);
        }
    }

    float hold[2][4] = {};

    __syncthreads();

    // t=0 (h=0) writes buf1; pairs keep compile-time buffer indices
    gru_step<false, 0>(0, x, rowbase, l15, lg, wv, lane, hl, wlds, wreg, wireg,
                       bR, bZ, bIN, bHN, hold, colA);
    for (int tt = 1; tt < SEQ - 1; tt += 2) {
        gru_step<true, 1>(tt,     x, rowbase, l15, lg, wv, lane, hl, wlds, wreg, wireg,
                          bR, bZ, bIN, bHN, hold, colA);
        gru_step<true, 0>(tt + 1, x, rowbase, l15, lg, wv, lane, hl, wlds, wreg, wireg,
                          bR, bZ, bIN, bHN, hold, colA);
    }
    gru_step<true, 1>(SEQ - 1, x, rowbase, l15, lg, wv, lane, hl, wlds, wreg, wireg,
                      bR, bZ, bIN, bHN, hold, colA);

    // ---- FC epilogue: h(SEQ) in buf0 (f32 `hold` would be better but is
    // column-distributed; bf16 h adds only ~1e-4 to out — negligible)
    float* hf = (float*)&wlds[0][0][0][0][0];   // overlay 16 KB on weight LDS
    {
        int r = tid >> 5, kg = tid & 31;
        #pragma unroll
        for (int e = 0; e < 8; ++e) {
            int k = kg * 8 + e;
            hf[r * 256 + k] = bf2f(hl[0][k >> 3][r][k & 7]);
        }
    }
    __syncthreads();
    if (tid < ROWS * N_OUT) {
        int r = tid / N_OUT, o = tid - r * N_OUT;
        float acc = fc_b[o];
        #pragma unroll
        for (int k4 = 0; k4 < 64; ++k4) {
            float4 hv = *(const float4*)&hf[r * 256 + k4 * 4];
            float4 wv4 = *(const float4*)&fc_w[o * 256 + k4 * 4];
            acc = fmaf(hv.x, wv4.x, acc);
            acc = fmaf(hv.y, wv4.y, acc);
            acc = fmaf(hv.z, wv4.z, acc);
            acc = fmaf(hv.w, wv4.w, acc);
        }
        out[(size_t)(rowbase + r) * N_OUT + o] = acc;
    }
}

extern "C" void kernel_launch(void* const* d_in, const int* in_sizes, int n_in,
                              void* d_out, int out_size, void* d_ws, size_t ws_size,
                              hipStream_t stream) {
    const float* x    = (const float*)d_in[0];
    const float* w_ih = (const float*)d_in[1];
    const float* w_hh = (const float*)d_in[2];
    const float* b_ih = (const float*)d_in[3];
    const float* b_hh = (const float*)d_in[4];
    const float* fc_w = (const float*)d_in[5];
    const float* fc_b = (const float*)d_in[6];
    float* out = (float*)d_out;

    short* wB = (short*)d_ws;                 // [768][256] bf16 = 384 KB
    short* wI = wB + G3 * N_MID;              // [768][32]  bf16 =  48 KB

    hipLaunchKernelGGL(prep_w, dim3(768), dim3(256), 0, stream, w_hh, w_ih, wB, wI);
    hipLaunchKernelGGL(gru_onecu, dim3(NBLK), dim3(THREADS), 0, stream,
                       x, wB, wI, b_ih, b_hh, fc_w, fc_b, out);
}